// Round 1
// 1146.606 us; speedup vs baseline: 1.0728x; 1.0728x over previous
//
#include <hip/hip_runtime.h>

// ---------------------------------------------------------------------------
// HebbianBlock: out(B,T,D) f32; chunked linear-attention style recurrence.
// Pipeline: cast->bf16 | w^T transpose | vT = Ww@rk^T (GEMM) |
//           scan(inter, W-state, 16-wave) | intra (S*M@v) |
//           y = out + alpha*(inter+intra)@Wr^T (GEMM)
// ---------------------------------------------------------------------------

typedef __attribute__((ext_vector_type(8))) short short8;
typedef __attribute__((ext_vector_type(4))) short short4v;
typedef __attribute__((ext_vector_type(4))) float f32x4;

#define B_ 4
#define T_ 8192
#define D_ 1024
#define C_ 64
#define NC_ 128

#define DEVI static __device__ __forceinline__

#define EXPF(x) __builtin_expf(x)
#define LOG2F(x) __builtin_log2f(x)
#define EXP2F(x) __builtin_exp2f(x)

DEVI unsigned short f2bf_u(float f) {
  unsigned int u = __float_as_uint(f);
  u += 0x7fffu + ((u >> 16) & 1u);   // round-to-nearest-even
  return (unsigned short)(u >> 16);
}
DEVI short f2bfs(float f) { return (short)f2bf_u(f); }
DEVI float bf2fs(short h) { return __uint_as_float(((unsigned int)(unsigned short)h) << 16); }

DEVI f32x4 mfma16(short8 a, short8 b, f32x4 c) {
  return __builtin_amdgcn_mfma_f32_16x16x32_bf16(a, b, c, 0, 0, 0);
}

// ---------------------------------------------------------------- cast f32->bf16
__global__ __launch_bounds__(256) void k_cast(const float* __restrict__ src,
                                              short* __restrict__ dst, int n8) {
  int i = blockIdx.x * 256 + threadIdx.x;
  if (i >= n8) return;
  const float4* s = (const float4*)src;
  float4 a = s[2 * i], b = s[2 * i + 1];
  short8 o;
  o[0] = f2bfs(a.x); o[1] = f2bfs(a.y); o[2] = f2bfs(a.z); o[3] = f2bfs(a.w);
  o[4] = f2bfs(b.x); o[5] = f2bfs(b.y); o[6] = f2bfs(b.z); o[7] = f2bfs(b.w);
  *((short8*)dst + i) = o;
}

// ---------------------------------------------------------------- w^T transpose
// wTg[b][e][t] = rk[b][t-1][e]  (pre-shifted: w_t = rk_{t-1}, t=0 -> 0)
__global__ __launch_bounds__(256) void k_transT(const short* __restrict__ rk,
                                                short* __restrict__ wTg) {
  __shared__ short ts[64][72];
  const int tid = threadIdx.x;
  const int t0 = blockIdx.x * 64, e0 = blockIdx.y * 64, b = blockIdx.z;
  const short* rk_b = rk + (size_t)b * T_ * D_;
  short* w_b = wTg + (size_t)b * D_ * T_;
  const int lr = tid >> 3, ls = tid & 7;   // 32 rows x 8 segs per pass
#pragma unroll
  for (int p = 0; p < 2; ++p) {
    int row = p * 32 + lr;                 // ts[row] holds rk[t0-1+row]
    int t = t0 - 1 + row;
    short8 v8;
    if (t >= 0) v8 = *(const short8*)(rk_b + (size_t)t * D_ + e0 + ls * 8);
    else v8 = (short8){0, 0, 0, 0, 0, 0, 0, 0};
    *(short8*)&ts[row][ls * 8] = v8;
  }
  __syncthreads();
  const int er5 = tid & 31, thi = tid >> 5;   // erow low-bits for bank spread
#pragma unroll
  for (int ep = 0; ep < 2; ++ep) {
    int erow = ep * 32 + er5;
    short8 w8;
#pragma unroll
    for (int j = 0; j < 8; ++j) w8[j] = ts[thi * 8 + j][erow];
    *(short8*)(w_b + (size_t)(e0 + erow) * T_ + t0 + thi * 8) = w8;
  }
}

// ---------------------------------------------------------------- vT = Ww @ rk^T
__global__ __launch_bounds__(256) void k_gemm_v(const short* __restrict__ Aw,
                                                const short* __restrict__ Bx,
                                                short* __restrict__ vT) {
  __shared__ short As[128][72];
  __shared__ short Bs[128][72];
  const int tid = threadIdx.x;
  const int lane = tid & 63, wv = tid >> 6;
  const int wm = (wv >> 1) * 64, wn = (wv & 1) * 64;
  const int l16 = lane & 15, q = lane >> 4;
  const int m0 = blockIdx.y * 128;
  const int n0 = blockIdx.x * 128;
  f32x4 acc[4][4];
  for (int a = 0; a < 4; ++a)
    for (int b = 0; b < 4; ++b) acc[a][b] = (f32x4){0.f, 0.f, 0.f, 0.f};
  const int lrow = tid >> 3, lseg = tid & 7;
  const short* Ap = Aw + (size_t)(m0 + lrow) * D_ + lseg * 8;
  const short* Bp = Bx + (size_t)(n0 + lrow) * D_ + lseg * 8;
  for (int kb = 0; kb < D_; kb += 64) {
#pragma unroll
    for (int p = 0; p < 4; ++p) {
      *(short8*)&As[lrow + p * 32][lseg * 8] = *(const short8*)(Ap + (size_t)(p * 32) * D_ + kb);
      *(short8*)&Bs[lrow + p * 32][lseg * 8] = *(const short8*)(Bp + (size_t)(p * 32) * D_ + kb);
    }
    __syncthreads();
#pragma unroll
    for (int ks = 0; ks < 2; ++ks) {
      short8 af[4], bfr[4];
#pragma unroll
      for (int mt = 0; mt < 4; ++mt) af[mt] = *(const short8*)&As[wm + mt * 16 + l16][ks * 32 + q * 8];
#pragma unroll
      for (int nt = 0; nt < 4; ++nt) bfr[nt] = *(const short8*)&Bs[wn + nt * 16 + l16][ks * 32 + q * 8];
#pragma unroll
      for (int mt = 0; mt < 4; ++mt)
#pragma unroll
        for (int nt = 0; nt < 4; ++nt) acc[mt][nt] = mfma16(af[mt], bfr[nt], acc[mt][nt]);
    }
    __syncthreads();
  }
  const int b = n0 >> 13;                // T_ = 8192 rows per batch
  const int tbase = (n0 & (T_ - 1)) + wn;
  short* outp = vT + (size_t)b * D_ * T_;
#pragma unroll
  for (int mt = 0; mt < 4; ++mt)
#pragma unroll
    for (int nt = 0; nt < 4; ++nt)
#pragma unroll
      for (int i = 0; i < 4; ++i) {
        int d = m0 + wm + mt * 16 + q * 4 + i;
        int t = tbase + nt * 16 + l16;
        outp[(size_t)d * T_ + t] = f2bfs(acc[mt][nt][i]);
      }
}

// ---------------------------------------------------------------- scan (inter + W state)
// grid (64 d-tiles, 4 batches), 1024 threads (16 waves, 4/SIMD).
// Per group (chunk ch, slice s of 256 e):
//   wave wv: GEMM1  inter-partial: c-tiles {2(wv&1), 2(wv&1)+1}, e-range (wv>>1)*32
//            GEMM2  W-update: its 16-wide e column (wv*16) of slice s
// w^T comes pre-transposed from wTg (no in-kernel transpose).
__global__ __launch_bounds__(1024) void k_scan(const short* __restrict__ rk,
                                               const short* __restrict__ vT_g,
                                               const short* __restrict__ wTg,
                                               short* __restrict__ inter_,
                                               const float* __restrict__ decay_p) {
  __shared__ short rs[64][264];      // r rows t0..t0+63, current 256-wide e-slice
  __shared__ short wT[256][72];      // w^T rows (e-local), 64 c cols, current slice
  __shared__ short Wb[16][1032];     // bf16 snapshot of W slice (chunk-start value)
  __shared__ short vTs[16][72];      // v^T slice scaled by gw[c]=gamma^(63-c)
  __shared__ float red[8][64][17];   // per-e-range inter partials (f32)

  const int tid = threadIdx.x;
  const int lane = tid & 63;
  const int wv = tid >> 6;                 // 0..15
  const int l16 = lane & 15, q = lane >> 4;
  const int dt = blockIdx.x, b = blockIdx.y;
  const int d0 = dt * 16;
  const float gamma = 1.f / (1.f + EXPF(-decay_p[0]));
  const float lg2g = LOG2F(gamma);
  const float gC = EXP2F(64.f * lg2g);

  const short* rk_b = rk + (size_t)b * T_ * D_;
  const short* wT_b = wTg + (size_t)b * D_ * T_;
  const short* vT_b = vT_g + (size_t)b * D_ * T_;

  // staging geometry (1024 threads move one 256-wide slice of rs + wT)
  const int srow = tid >> 5;               // 0..31  (rs rows, 2 passes)
  const int sseg = tid & 31;               // 16B segment in a 512B row
  const int erow = tid >> 3;               // 0..127 (wT rows, 2 passes)
  const int tseg = tid & 7;                // 16B segment in a 128B row

  // vTs staging role: threads [512,768)
  const bool vrole = (tid >= 512 && tid < 768);
  const int vd = (tid - 512) >> 4;
  const int vc4 = ((tid - 512) & 15) << 2;
  const short* vptr = vT_b + (size_t)(d0 + vd) * T_ + vc4;

  const int ew = (wv >> 1) * 32;           // GEMM1 e-range within slice
  const int cpair = (wv & 1) * 2;          // GEMM1 c-tile base

  f32x4 Wacc[4];
#pragma unroll
  for (int j = 0; j < 4; ++j) Wacc[j] = (f32x4){0.f, 0.f, 0.f, 0.f};
  f32x4 iacc[2];
  iacc[0] = (f32x4){0.f, 0.f, 0.f, 0.f};
  iacc[1] = (f32x4){0.f, 0.f, 0.f, 0.f};

  short8 pf0, pf1, pf2, pf3;
  short4v vpre;

  auto issue_pf = [&](int g) {             // g = global slice index (ch*4+s)
    int nch = g >> 2, ns = g & 3;
    const short* rsrc = rk_b + (size_t)(nch * 64 + srow) * D_ + ns * 256 + sseg * 8;
    pf0 = *(const short8*)rsrc;
    pf1 = *(const short8*)(rsrc + (size_t)32 * D_);
    const short* wsrc = wT_b + (size_t)(ns * 256 + erow) * T_ + nch * 64 + tseg * 8;
    pf2 = *(const short8*)wsrc;
    pf3 = *(const short8*)(wsrc + (size_t)128 * T_);
  };
  auto write_pf = [&]() {
    *(short8*)&rs[srow][sseg * 8] = pf0;
    *(short8*)&rs[srow + 32][sseg * 8] = pf1;
    *(short8*)&wT[erow][tseg * 8] = pf2;
    *(short8*)&wT[erow + 128][tseg * 8] = pf3;
  };
  auto write_vTs = [&]() {
#pragma unroll
    for (int j = 0; j < 4; ++j)
      vTs[vd][vc4 + j] = f2bfs(bf2fs(vpre[j]) * EXP2F(lg2g * (float)(63 - (vc4 + j))));
  };

  // ---- prologue: stage slice (ch=0,s=0), vTs for ch=0, zero Wb
  issue_pf(0);
  if (vrole) vpre = *(const short4v*)vptr;
  write_pf();
  if (vrole) write_vTs();
  {
    short4v z4 = (short4v){0, 0, 0, 0};
    for (int i = tid; i < (16 * 1032) / 4; i += 1024) ((short4v*)&Wb[0][0])[i] = z4;
  }
  __syncthreads();

  for (int ch = 0; ch < NC_; ++ch) {
    // v^T A-fragments held in regs for the whole chunk (reused by every group)
    short8 a2k0 = *(const short8*)&vTs[l16][q * 8];
    short8 a2k1 = *(const short8*)&vTs[l16][32 + q * 8];
#pragma unroll
    for (int s = 0; s < 4; ++s) {
      const int g = ch * 4 + s;
      // phase A: prefetch next slice + compute current
      if (g + 1 < 512) issue_pf(g + 1);
      if (s == 3 && vrole && ch + 1 < NC_) vpre = *(const short4v*)(vptr + (ch + 1) * 64);
      // GEMM1: inter partial (c x 16d over this wave's 32-wide e-range)
      short8 bfr1 = *(const short8*)&Wb[l16][s * 256 + ew + q * 8];
      short8 af0 = *(const short8*)&rs[cpair * 16 + l16][ew + q * 8];
      short8 af1 = *(const short8*)&rs[(cpair + 1) * 16 + l16][ew + q * 8];
      iacc[0] = mfma16(af0, bfr1, iacc[0]);
      iacc[1] = mfma16(af1, bfr1, iacc[1]);
      // GEMM2: W[d, e=s*256+wv*16+l16] += vg^T @ w  (K = 64 c)
      short8 bw0 = *(const short8*)&wT[wv * 16 + l16][q * 8];
      short8 bw1 = *(const short8*)&wT[wv * 16 + l16][32 + q * 8];
      Wacc[s] = mfma16(a2k0, bw0, Wacc[s]);
      Wacc[s] = mfma16(a2k1, bw1, Wacc[s]);
      __syncthreads();               // B: all reads of slice s done
      // phase B: land prefetched slice
      if (g + 1 < 512) write_pf();
      if (s < 3) {
        __syncthreads();             // A: slice s+1 ready
      } else {
        // ---- chunk epilogue ----
        // 1) dump inter partials (f32) + reset
#pragma unroll
        for (int u = 0; u < 2; ++u)
#pragma unroll
          for (int i = 0; i < 4; ++i) {
            red[wv >> 1][(cpair + u) * 16 + q * 4 + i][l16] = iacc[u][i];
            iacc[u][i] = 0.f;
          }
        // 2) snapshot W_k (pre-decay) for next chunk's GEMM1, then decay state
#pragma unroll
        for (int s2 = 0; s2 < 4; ++s2)
#pragma unroll
          for (int i = 0; i < 4; ++i) {
            Wb[q * 4 + i][s2 * 256 + wv * 16 + l16] = f2bfs(Wacc[s2][i]);
            Wacc[s2][i] *= gC;
          }
        // 3) stage next chunk's scaled v^T
        if (vrole && ch + 1 < NC_) write_vTs();
        __syncthreads();             // E: red/Wb/vTs ready
        // 4) reduce 8 e-range partials, scale by gamma^c, store bf16
        {
          int c = tid >> 4, d = tid & 15;
          float sum = 0.f;
#pragma unroll
          for (int p = 0; p < 8; ++p) sum += red[p][c][d];
          inter_[(size_t)b * T_ * D_ + (size_t)(ch * 64 + c) * D_ + d0 + d] =
              f2bfs(sum * EXP2F(lg2g * (float)c));
        }
      }
    }
  }
}

// ---------------------------------------------------------------- intra chunk
__global__ __launch_bounds__(256) void k_intra(const short* __restrict__ rk,
                                               const short* __restrict__ vT_g,
                                               short* __restrict__ intra_,
                                               const float* __restrict__ decay_p) {
  __shared__ short rs[65][264];
  __shared__ short P[64][72];
  __shared__ short vs[256][72];
  const int tid = threadIdx.x;
  const int lane = tid & 63, wv = tid >> 6;
  const int l16 = lane & 15, q = lane >> 4;
  const int ch = blockIdx.x, b = blockIdx.y;
  const int t0 = ch << 6;
  const float gamma = 1.f / (1.f + EXPF(-decay_p[0]));
  const float lg2g = LOG2F(gamma);
  const short* rk_b = rk + (size_t)b * T_ * D_;
  f32x4 Sacc[4];
#pragma unroll
  for (int j = 0; j < 4; ++j) Sacc[j] = (f32x4){0.f, 0.f, 0.f, 0.f};

  for (int s = 0; s < 4; ++s) {
    const int e0 = s << 8;
#pragma unroll
    for (int p = 0; p < 9; ++p) {
      int idx = p * 256 + tid;
      if (idx < 2080) {
        int row = idx >> 5, seg = idx & 31;
        int t = t0 - 1 + row;
        short8 v8;
        if (t >= 0) v8 = *(const short8*)(rk_b + (size_t)t * D_ + e0 + seg * 8);
        else v8 = (short8){0, 0, 0, 0, 0, 0, 0, 0};
        *(short8*)&rs[row][seg * 8] = v8;
      }
    }
    __syncthreads();
#pragma unroll
    for (int ks = 0; ks < 8; ++ks) {
      short8 af = *(const short8*)&rs[wv * 16 + l16 + 1][ks * 32 + q * 8];   // r rows
#pragma unroll
      for (int nt = 0; nt < 4; ++nt) {
        short8 bfr = *(const short8*)&rs[nt * 16 + l16][ks * 32 + q * 8];    // w rows
        Sacc[nt] = mfma16(af, bfr, Sacc[nt]);
      }
    }
    __syncthreads();
  }
  // mask: P[c][c'] = S * gamma^(c-1-c') for c>c', else 0
#pragma unroll
  for (int nt = 0; nt < 4; ++nt)
#pragma unroll
    for (int i = 0; i < 4; ++i) {
      int c = wv * 16 + q * 4 + i;
      int cp = nt * 16 + l16;
      float m = (c > cp) ? EXP2F(lg2g * (float)(c - 1 - cp)) : 0.f;
      P[c][cp] = f2bfs(Sacc[nt][i] * m);
    }
  __syncthreads();
  const short* vsrc = vT_g + (size_t)b * D_ * T_ + (size_t)tid * T_ + t0;
  size_t base = (size_t)b * T_ * D_;
  for (int p = 0; p < 4; ++p) {
    const short* sp = vsrc + (size_t)(p * 256) * T_;
#pragma unroll
    for (int seg = 0; seg < 8; ++seg)
      *(short8*)&vs[tid][seg * 8] = *(const short8*)(sp + seg * 8);
    __syncthreads();
    f32x4 acc[4][4];
#pragma unroll
    for (int a = 0; a < 4; ++a)
#pragma unroll
      for (int bb = 0; bb < 4; ++bb) acc[a][bb] = (f32x4){0.f, 0.f, 0.f, 0.f};
#pragma unroll
    for (int ks2 = 0; ks2 < 2; ++ks2) {
      short8 af[4];
#pragma unroll
      for (int mt = 0; mt < 4; ++mt) af[mt] = *(const short8*)&P[mt * 16 + l16][ks2 * 32 + q * 8];
#pragma unroll
      for (int nt = 0; nt < 4; ++nt) {
        short8 bfr = *(const short8*)&vs[wv * 64 + nt * 16 + l16][ks2 * 32 + q * 8];
#pragma unroll
        for (int mt = 0; mt < 4; ++mt) acc[mt][nt] = mfma16(af[mt], bfr, acc[mt][nt]);
      }
    }
#pragma unroll
    for (int mt = 0; mt < 4; ++mt)
#pragma unroll
      for (int nt = 0; nt < 4; ++nt)
#pragma unroll
        for (int i = 0; i < 4; ++i) {
          int c = mt * 16 + q * 4 + i;
          int d = p * 256 + wv * 64 + nt * 16 + l16;
          intra_[base + (size_t)(t0 + c) * D_ + d] = f2bfs(acc[mt][nt][i]);
        }
    __syncthreads();
  }
}

// ---------------------------------------------------------------- final GEMM
__global__ __launch_bounds__(256) void k_gemm_final(const short* __restrict__ inter_,
                                                    const short* __restrict__ intra_,
                                                    const short* __restrict__ Wr,
                                                    const float* __restrict__ xin,
                                                    float* __restrict__ y,
                                                    const float* __restrict__ la_p) {
  __shared__ short As[128][72];
  __shared__ short Bs[128][72];
  const float alpha = EXPF(la_p[0]);
  const int tid = threadIdx.x;
  const int lane = tid & 63, wv = tid >> 6;
  const int wm = (wv >> 1) * 64, wn = (wv & 1) * 64;
  const int l16 = lane & 15, q = lane >> 4;
  const int m0 = blockIdx.x * 128;
  const int n0 = blockIdx.y * 128;
  f32x4 acc[4][4];
  for (int a = 0; a < 4; ++a)
    for (int b = 0; b < 4; ++b) acc[a][b] = (f32x4){0.f, 0.f, 0.f, 0.f};
  const int lrow = tid >> 3, lseg = tid & 7;
  for (int kb = 0; kb < D_; kb += 64) {
#pragma unroll
    for (int p = 0; p < 4; ++p) {
      size_t aoff = (size_t)(m0 + lrow + p * 32) * D_ + kb + lseg * 8;
      short8 xa = *(const short8*)(inter_ + aoff);
      short8 xb = *(const short8*)(intra_ + aoff);
      short8 xs;
#pragma unroll
      for (int j = 0; j < 8; ++j) xs[j] = f2bfs(bf2fs(xa[j]) + bf2fs(xb[j]));
      *(short8*)&As[lrow + p * 32][lseg * 8] = xs;
      *(short8*)&Bs[lrow + p * 32][lseg * 8] =
          *(const short8*)(Wr + (size_t)(n0 + lrow + p * 32) * D_ + kb + lseg * 8);
    }
    __syncthreads();
#pragma unroll
    for (int ks = 0; ks < 2; ++ks) {
      short8 af[4], bfr[4];
#pragma unroll
      for (int mt = 0; mt < 4; ++mt) af[mt] = *(const short8*)&As[wm + mt * 16 + l16][ks * 32 + q * 8];
#pragma unroll
      for (int nt = 0; nt < 4; ++nt) bfr[nt] = *(const short8*)&Bs[wn + nt * 16 + l16][ks * 32 + q * 8];
#pragma unroll
      for (int mt = 0; mt < 4; ++mt)
#pragma unroll
        for (int nt = 0; nt < 4; ++nt) acc[mt][nt] = mfma16(af[mt], bfr[nt], acc[mt][nt]);
    }
    __syncthreads();
  }
#pragma unroll
  for (int mt = 0; mt < 4; ++mt)
#pragma unroll
    for (int nt = 0; nt < 4; ++nt)
#pragma unroll
      for (int i = 0; i < 4; ++i) {
        int t = m0 + wm + mt * 16 + q * 4 + i;
        int d = n0 + wn + nt * 16 + l16;
        size_t idx = (size_t)t * D_ + d;
        y[idx] = xin[idx] + alpha * acc[mt][nt][i];
      }
}

// ---------------------------------------------------------------- launch
extern "C" void kernel_launch(void* const* d_in, const int* in_sizes, int n_in,
                              void* d_out, int out_size, void* d_ws, size_t ws_size,
                              hipStream_t stream) {
  const float* x = (const float*)d_in[0];
  const float* Ww = (const float*)d_in[1];
  const float* Wr = (const float*)d_in[2];
  const float* decay = (const float*)d_in[3];
  const float* log_alpha = (const float*)d_in[4];
  float* y = (float*)d_out;

  short* ws = (short*)d_ws;
  const size_t NTD = (size_t)B_ * T_ * D_;   // 33,554,432
  short* rk_bf = ws;
  short* vT_bf = rk_bf + NTD;
  short* inter_b = vT_bf + NTD;
  short* intra_b = inter_b + NTD;
  short* Ww_bf = intra_b + NTD;
  short* Wr_bf = Ww_bf + (size_t)D_ * D_;
  // wTg aliases intra_b: only live between k_transT and k_scan; k_intra
  // overwrites it afterwards. total ws use unchanged: 4*NTD + 2*D*D shorts.
  short* wTg = intra_b;

  k_cast<<<(int)(NTD / 8 / 256), 256, 0, stream>>>(x, rk_bf, (int)(NTD / 8));
  k_cast<<<512, 256, 0, stream>>>(Ww, Ww_bf, (D_ * D_) / 8);
  k_cast<<<512, 256, 0, stream>>>(Wr, Wr_bf, (D_ * D_) / 8);
  k_transT<<<dim3(T_ / 64, D_ / 64, B_), 256, 0, stream>>>(rk_bf, wTg);
  k_gemm_v<<<dim3(256, 8), 256, 0, stream>>>(Ww_bf, rk_bf, vT_bf);
  k_scan<<<dim3(64, 4), 1024, 0, stream>>>(rk_bf, vT_bf, wTg, inter_b, decay);
  k_intra<<<dim3(128, 4), 256, 0, stream>>>(rk_bf, vT_bf, intra_b, decay);
  k_gemm_final<<<dim3(256, 8), 256, 0, stream>>>(inter_b, intra_b, Wr_bf, x, y, log_alpha);
}